// Round 11
// baseline (579.227 us; speedup 1.0000x reference)
//
#include <hip/hip_runtime.h>
#include <hip/hip_bf16.h>

typedef __hip_bfloat16 bf16;
typedef __attribute__((ext_vector_type(8))) short short8;
typedef __attribute__((ext_vector_type(4))) short s16x4;
typedef __attribute__((ext_vector_type(4))) float f32x4;

__device__ __forceinline__ float s2f(short s) {
    unsigned u = ((unsigned)(unsigned short)s) << 16;
    return __builtin_bit_cast(float, u);
}
__device__ __forceinline__ short f2s(float f) {
    bf16 h = __float2bfloat16(f);
    return __builtin_bit_cast(short, h);
}
__device__ __forceinline__ void gload_lds16(const void* g, void* l) {
    __builtin_amdgcn_global_load_lds(
        (const __attribute__((address_space(1))) unsigned int*)g,
        (__attribute__((address_space(3))) unsigned int*)l, 16, 0, 0);
}

#define PH_VM8  asm volatile("s_waitcnt vmcnt(8)" ::: "memory")
#define PH_VM4  asm volatile("s_waitcnt vmcnt(4)" ::: "memory")
#define PH_VM0  asm volatile("s_waitcnt vmcnt(0)" ::: "memory")
#define PH_BAR  __builtin_amdgcn_s_barrier()
#define PH_LGKM do { asm volatile("s_waitcnt lgkmcnt(0)" ::: "memory"); \
                     __builtin_amdgcn_sched_barrier(0); } while (0)

// ---------------- convert+transpose: src fp32 [R][C] -> dst bf16 [C][R] ----------------
__global__ __launch_bounds__(256) void tconv_kernel(const float* __restrict__ src,
                                                    short* __restrict__ dst,
                                                    int R, int C) {
    __shared__ short tile[64][65];
    const int r0 = blockIdx.y * 64, c0 = blockIdx.x * 64;
    const int t = threadIdx.x;
    const int lr = t >> 2, lc = (t & 3) * 16;
    const float* sp = src + (size_t)(r0 + lr) * C + c0 + lc;
#pragma unroll
    for (int q = 0; q < 4; q++) {
        f32x4 v = *(const f32x4*)(const void*)(sp + q * 4);
#pragma unroll
        for (int j = 0; j < 4; j++) tile[lr][lc + q * 4 + j] = f2s(v[j]);
    }
    __syncthreads();
    short8 o0, o1;
#pragma unroll
    for (int j = 0; j < 8; j++) { o0[j] = tile[lc + j][lr]; o1[j] = tile[lc + 8 + j][lr]; }
    short* dp = dst + (size_t)(c0 + lr) * R + r0 + lc;
    *(short8*)(void*)dp = o0;
    *(short8*)(void*)(dp + 8) = o1;
}

// ---------------- LayerNorm: wave-per-row, 4 rows/block, fp32 in -> bf16 out ----------------
__global__ __launch_bounds__(256) void ln_kernel(const float* __restrict__ x,
                                                 const float* __restrict__ g,
                                                 const float* __restrict__ beta,
                                                 bf16* __restrict__ out) {
    const int t = threadIdx.x;
    const int w = t >> 6, lane = t & 63;
    const int row = blockIdx.x * 4 + w;
    const float* xr = x + (size_t)row * 1024;
    float v[16];
    float s = 0.f, ss = 0.f;
#pragma unroll
    for (int p = 0; p < 4; p++) {
        f32x4 xv = *(const f32x4*)(const void*)(xr + p * 256 + lane * 4);
#pragma unroll
        for (int j = 0; j < 4; j++) {
            v[p * 4 + j] = xv[j];
            s += xv[j];
            ss += xv[j] * xv[j];
        }
    }
#pragma unroll
    for (int off = 32; off >= 1; off >>= 1) {
        s += __shfl_xor(s, off);
        ss += __shfl_xor(ss, off);
    }
    const float mu = s * (1.0f / 1024.0f);
    const float var = ss * (1.0f / 1024.0f) - mu * mu;
    const float rstd = rsqrtf(var + 1e-5f);
    short* orow = (short*)(void*)(out + (size_t)row * 1024);
#pragma unroll
    for (int p = 0; p < 4; p++) {
        const int c = p * 256 + lane * 4;
        f32x4 gv = *(const f32x4*)(const void*)(g + c);
        f32x4 bv = *(const f32x4*)(const void*)(beta + c);
        s16x4 o;
#pragma unroll
        for (int j = 0; j < 4; j++)
            o[j] = f2s((v[p * 4 + j] - mu) * rstd * gv[j] + bv[j]);
        *(s16x4*)(void*)(orow + c) = o;
    }
}

// ---------------- GEMM 128x128, BK=64: 4-phase counted-vmcnt core (Wo, W2) ----------
// (round-10 proven)
#define MM_BLK2(ACC)                                                         \
    do {                                                                     \
        __builtin_amdgcn_s_setprio(1);                                       \
        _Pragma("unroll")                                                    \
        for (int mi_ = 0; mi_ < 2; mi_++)                                    \
            _Pragma("unroll")                                                \
            for (int ni_ = 0; ni_ < 4; ni_++)                                \
                ACC[mi_][ni_] = __builtin_amdgcn_mfma_f32_16x16x32_bf16(     \
                    af[mi_], bf[ni_], ACC[mi_][ni_], 0, 0, 0);               \
        __builtin_amdgcn_s_setprio(0);                                       \
    } while (0)

__global__ __launch_bounds__(256, 2) void gemm128(const bf16* __restrict__ A,
                                                  const bf16* __restrict__ Bt,
                                                  const float* __restrict__ bias,
                                                  const float* resid,
                                                  void* Cp, int c_f32,
                                                  int m_base, int N, int K,
                                                  int relu_flag) {
    __shared__ char lds[65536];
    const int NT = K >> 6;

    const int t = threadIdx.x;
    const int w = t >> 6, lane = t & 63;
    const int l = lane & 15, g = lane >> 4;
    const int m0 = blockIdx.x * 128, n0 = blockIdx.y * 128;
    const int wm = (w >> 1) * 64, wn = (w & 1) * 64;
    const int qx = (g ^ ((l >> 1) & 3)) * 16;
    const int qh8 = (((lane & 3) ^ ((lane >> 3) & 3)) * 8);
    const int srow = w * 32 + (lane >> 2);
    const short* Asrc = (const short*)A;
    const short* Bsrc = (const short*)Bt;

    f32x4 accL[2][4] = {};
    f32x4 accH[2][4] = {};
    short8 af[2], bf[4];

    auto stage = [&](int th, int j) {
        const int ks = j >> 1, mat = j & 1;
        char* slot = lds + ((th & 1) << 15) + (mat << 14) + (ks << 13);
        const short* mp = mat ? Bsrc : Asrc;
        const int rowb = (mat ? n0 : m0);
        const int kc = th * 64 + ks * 32 + qh8;
        gload_lds16(mp + (size_t)(rowb + srow) * K + kc,      slot + w * 2048);
        gload_lds16(mp + (size_t)(rowb + srow + 16) * K + kc, slot + w * 2048 + 1024);
    };
    auto lda_ = [&](const char* rb, int mi, int ks) -> short8 {
        return *(const short8*)(rb + (ks << 13) + (wm + mi * 16 + l) * 64 + qx);
    };
    auto ldb_ = [&](const char* rb, int ni, int ks) -> short8 {
        return *(const short8*)(rb + 16384 + (ks << 13) + (wn + ni * 16 + l) * 64 + qx);
    };

    stage(0, 0); stage(0, 1); stage(0, 2); stage(0, 3); stage(1, 0); stage(1, 1);

    for (int it = 0; it < NT - 1; ++it) {
        const char* rb = lds + ((it & 1) << 15);
        PH_VM8; PH_BAR;
        af[0] = lda_(rb, 0, 0); af[1] = lda_(rb, 1, 0);
#pragma unroll
        for (int i = 0; i < 4; i++) bf[i] = ldb_(rb, i, 0);
        stage(it + 1, 2);
        PH_LGKM;
        MM_BLK2(accL);
        af[0] = lda_(rb, 2, 0); af[1] = lda_(rb, 3, 0);
        stage(it + 1, 3);
        PH_BAR; PH_LGKM;
        MM_BLK2(accH);
        PH_VM8; PH_BAR;
        af[0] = lda_(rb, 0, 1); af[1] = lda_(rb, 1, 1);
#pragma unroll
        for (int i = 0; i < 4; i++) bf[i] = ldb_(rb, i, 1);
        if (it + 2 < NT) stage(it + 2, 0);
        PH_LGKM;
        MM_BLK2(accL);
        af[0] = lda_(rb, 2, 1); af[1] = lda_(rb, 3, 1);
        if (it + 2 < NT) stage(it + 2, 1);
        PH_BAR; PH_LGKM;
        MM_BLK2(accH);
    }
    {
        const char* rb = lds + (((NT - 1) & 1) << 15);
        PH_VM4; PH_BAR;
        af[0] = lda_(rb, 0, 0); af[1] = lda_(rb, 1, 0);
#pragma unroll
        for (int i = 0; i < 4; i++) bf[i] = ldb_(rb, i, 0);
        PH_LGKM;
        MM_BLK2(accL);
        af[0] = lda_(rb, 2, 0); af[1] = lda_(rb, 3, 0);
        PH_BAR; PH_LGKM;
        MM_BLK2(accH);
        PH_VM0; PH_BAR;
        af[0] = lda_(rb, 0, 1); af[1] = lda_(rb, 1, 1);
#pragma unroll
        for (int i = 0; i < 4; i++) bf[i] = ldb_(rb, i, 1);
        PH_LGKM;
        MM_BLK2(accL);
        af[0] = lda_(rb, 2, 1); af[1] = lda_(rb, 3, 1);
        PH_BAR; PH_LGKM;
        MM_BLK2(accH);
    }

#pragma unroll
    for (int half = 0; half < 2; half++)
#pragma unroll
        for (int mi = 0; mi < 2; mi++)
#pragma unroll
            for (int r = 0; r < 4; r++) {
                const int grow = m_base + m0 + wm + (half * 2 + mi) * 16 + g * 4 + r;
                const size_t rowoff = (size_t)grow * N;
#pragma unroll
                for (int ni = 0; ni < 4; ni++) {
                    const int gcol = n0 + wn + ni * 16 + l;
                    float val = half ? accH[mi][ni][r] : accL[mi][ni][r];
                    if (bias) val += bias[gcol];
                    if (relu_flag) val = fmaxf(val, 0.f);
                    const size_t ci = rowoff + gcol;
                    if (resid) val += resid[ci];
                    if (c_f32) ((float*)Cp)[ci] = val;
                    else       ((short*)Cp)[ci] = f2s(val);
                }
            }
}

// ---------------- GEMM 256x256, BK=64, K=1024 fixed: 8-phase counted-vmcnt core ----
// (round-4 exact — proven in r4/r6/r7/r9/r10)
#define MM_BLOCK(ACC)                                                        \
    do {                                                                     \
        __builtin_amdgcn_s_setprio(1);                                       \
        _Pragma("unroll")                                                    \
        for (int mi_ = 0; mi_ < 4; mi_++)                                    \
            _Pragma("unroll")                                                \
            for (int ni_ = 0; ni_ < 4; ni_++)                                \
                ACC[mi_][ni_] = __builtin_amdgcn_mfma_f32_16x16x32_bf16(     \
                    af[mi_], bf[ni_], ACC[mi_][ni_], 0, 0, 0);               \
        __builtin_amdgcn_s_setprio(0);                                       \
    } while (0)

__global__ __launch_bounds__(512, 2) void gemm256(const bf16* __restrict__ A,
                                                  const bf16* __restrict__ Bt,
                                                  const float* __restrict__ bias,
                                                  bf16* __restrict__ Cp,
                                                  int N, int relu_flag) {
    __shared__ char lds[131072];
    constexpr int NT = 16;   // K = 1024 = NT * 64

    const int t = threadIdx.x;
    const int w = t >> 6, lane = t & 63;
    const int l = lane & 15, g = lane >> 4;
    const int m0 = blockIdx.x * 256, n0 = blockIdx.y * 256;
    const int wm = (w >> 2) * 128, wn = (w & 3) * 64;
    const int qx = (g ^ ((l >> 1) & 3)) * 16;
    const int qh8 = (((lane & 3) ^ ((lane >> 3) & 3)) * 8);
    const int srow = w * 32 + (lane >> 2);
    const short* Asrc = (const short*)A;
    const short* Bsrc = (const short*)Bt;

    f32x4 accL[4][4] = {};
    f32x4 accH[4][4] = {};
    short8 af[4], bf[4];

    auto stage = [&](int th, int j) {
        const int ks = j >> 1, mat = j & 1;
        char* slot = lds + ((th & 1) << 16) + (mat << 15) + (ks << 14);
        const short* mp = mat ? Bsrc : Asrc;
        const int rowb = (mat ? n0 : m0);
        const int kc = th * 64 + ks * 32 + qh8;
        gload_lds16(mp + (size_t)(rowb + srow) * 1024 + kc,      slot + (w * 2) * 1024);
        gload_lds16(mp + (size_t)(rowb + srow + 16) * 1024 + kc, slot + (w * 2 + 1) * 1024);
    };
    auto lda = [&](const char* rb, int mi, int ks) -> short8 {
        return *(const short8*)(rb + (ks << 14) + (wm + mi * 16 + l) * 64 + qx);
    };
    auto ldb = [&](const char* rb, int ni, int ks) -> short8 {
        return *(const short8*)(rb + 32768 + (ks << 14) + (wn + ni * 16 + l) * 64 + qx);
    };

    stage(0, 0); stage(0, 1); stage(0, 2); stage(0, 3); stage(1, 0); stage(1, 1);

    for (int it = 0; it < NT - 1; ++it) {
        const char* rb = lds + ((it & 1) << 16);
        PH_VM8; PH_BAR;
#pragma unroll
        for (int i = 0; i < 4; i++) af[i] = lda(rb, i, 0);
#pragma unroll
        for (int i = 0; i < 4; i++) bf[i] = ldb(rb, i, 0);
        stage(it + 1, 2);
        PH_LGKM;
        MM_BLOCK(accL);
#pragma unroll
        for (int i = 0; i < 4; i++) af[i] = lda(rb, 4 + i, 0);
        stage(it + 1, 3);
        PH_BAR; PH_LGKM;
        MM_BLOCK(accH);
        PH_VM8; PH_BAR;
#pragma unroll
        for (int i = 0; i < 4; i++) af[i] = lda(rb, i, 1);
#pragma unroll
        for (int i = 0; i < 4; i++) bf[i] = ldb(rb, i, 1);
        if (it + 2 < NT) stage(it + 2, 0);
        PH_LGKM;
        MM_BLOCK(accL);
#pragma unroll
        for (int i = 0; i < 4; i++) af[i] = lda(rb, 4 + i, 1);
        if (it + 2 < NT) stage(it + 2, 1);
        PH_BAR; PH_LGKM;
        MM_BLOCK(accH);
    }
    {
        const char* rb = lds + (((NT - 1) & 1) << 16);
        PH_VM4; PH_BAR;
#pragma unroll
        for (int i = 0; i < 4; i++) af[i] = lda(rb, i, 0);
#pragma unroll
        for (int i = 0; i < 4; i++) bf[i] = ldb(rb, i, 0);
        PH_LGKM;
        MM_BLOCK(accL);
#pragma unroll
        for (int i = 0; i < 4; i++) af[i] = lda(rb, 4 + i, 0);
        PH_BAR; PH_LGKM;
        MM_BLOCK(accH);
        PH_VM0; PH_BAR;
#pragma unroll
        for (int i = 0; i < 4; i++) af[i] = lda(rb, i, 1);
#pragma unroll
        for (int i = 0; i < 4; i++) bf[i] = ldb(rb, i, 1);
        PH_LGKM;
        MM_BLOCK(accL);
#pragma unroll
        for (int i = 0; i < 4; i++) af[i] = lda(rb, 4 + i, 1);
        PH_BAR; PH_LGKM;
        MM_BLOCK(accH);
    }

#pragma unroll
    for (int half = 0; half < 2; half++)
#pragma unroll
        for (int mi = 0; mi < 4; mi++)
#pragma unroll
            for (int r = 0; r < 4; r++) {
                const int grow = m0 + wm + (half * 4 + mi) * 16 + g * 4 + r;
                short* crow = (short*)(void*)Cp + (size_t)grow * N;
#pragma unroll
                for (int ni = 0; ni < 4; ni++) {
                    const int gcol = n0 + wn + ni * 16 + l;
                    float val = half ? accH[mi][ni][r] : accL[mi][ni][r];
                    if (bias) val += bias[gcol];
                    if (relu_flag) val = fmaxf(val, 0.f);
                    crow[gcol] = f2s(val);
                }
            }
}

// ---------------- MFMA flash attention: swapped QK^T, VALU-trimmed softmax ----------
// vs r10: (1) exp scale folded into qf (0.125*log2e) -> raw v_exp_f32, no
// per-element mul; (2) no -12 bias: S accum starts from zero quad passed as
// MFMA C operand (shift cancels in O = PV/l), killing 32 v_mov/tile;
// (3) row-sums via ones-MFMA on the idle matrix pipe (r6-proven fragment +
// epilogue) instead of 32 lane-local v_adds.
__global__ __launch_bounds__(256) void attn_kernel(const bf16* __restrict__ qkv,
                                                   bf16* __restrict__ o) {
    __shared__ short KsF[2][4096];
    __shared__ short Vt[64][72];
    __shared__ short Pl[4][32][76];

    const int bh = blockIdx.x;
    const int b = bh >> 4, h = bh & 15;
    const int qt = 15 - blockIdx.y;
    const int q0 = qt * 128;
    const size_t rbase = (size_t)b * 2048;
    const int hcol = h * 64;

    const int t = threadIdx.x;
    const int w = t >> 6;
    const int lane = t & 63;
    const int l = lane & 15;
    const int g = lane >> 4;
    const int sp = t >> 3;
    const int sb = (t & 7) * 8;

    const int qw0 = q0 + 32 * w;
    short8 qf[2][2];
#pragma unroll
    for (int mi = 0; mi < 2; mi++)
#pragma unroll
        for (int ks = 0; ks < 2; ks++) {
            const short* qp = (const short*)qkv +
                (rbase + qw0 + mi * 16 + l) * 3072 + hcol + ks * 32 + g * 8;
            short8 tv = *(const short8*)(const void*)qp;
            short8 sv;
#pragma unroll
            for (int e = 0; e < 8; e++) sv[e] = f2s(s2f(tv[e]) * 0.18033688f); // 0.125*log2(e)
            qf[mi][ks] = sv;
        }

    const int key_a = w * 16 + (lane >> 3);
    const int kd = (lane & 7) ^ ((lane >> 3) & 7);
    const short* kgA = (const short*)qkv + (rbase + key_a) * 3072 + 1024 + hcol + kd * 8;
    const short* kgB = kgA + 8 * 3072;

    f32x4 o_acc[2][4] = {};
    f32x4 l_acc[2] = {};
    const f32x4 z4 = {0.f, 0.f, 0.f, 0.f};
    short8 onesf;
    {
        const short ov = (l == 0) ? (short)0x3F80 : (short)0;
#pragma unroll
        for (int e = 0; e < 8; e++) onesf[e] = ov;
    }

    const int kt_max = (q0 + 127) >> 6;

    gload_lds16(kgA, &KsF[0][w * 1024]);
    gload_lds16(kgB, &KsF[0][w * 1024 + 512]);

    for (int kt = 0; kt <= kt_max; kt++) {
        const int k0 = kt * 64;
        const short* vg = (const short*)qkv + (rbase + k0 + 2 * sp) * 3072 + 2048 + hcol + sb;
        short8 vv0 = *(const short8*)(const void*)vg;
        short8 vv1 = *(const short8*)(const void*)(vg + 3072);
        PH_BAR;
        {
            const int kp = (kt < kt_max) ? (kt + 1) : kt;
            const size_t kof = (size_t)kp * 64 * 3072;
            gload_lds16(kgA + kof, &KsF[(kt + 1) & 1][w * 1024]);
            gload_lds16(kgB + kof, &KsF[(kt + 1) & 1][w * 1024 + 512]);
        }
        asm volatile("s_waitcnt vmcnt(2)" ::: "memory");
        __builtin_amdgcn_sched_barrier(0);
        {
            const int key = 2 * sp;
            const int cbk = key >> 3;
            const int kin = key & 7;
#pragma unroll
            for (int j = 0; j < 8; j++) {
                const int d = sb + j;
                const int col = ((cbk ^ (d >> 3)) << 3) + kin;
                int pk = (int)(unsigned short)vv0[j] | ((int)(unsigned short)vv1[j] << 16);
                *(int*)(void*)&Vt[d][col] = pk;
            }
        }
        asm volatile("s_waitcnt lgkmcnt(0)" ::: "memory");
        __builtin_amdgcn_sched_barrier(0);
        PH_BAR;

        if (k0 <= qw0 + 31) {
            const short* kb = &KsF[kt & 1][0];
            const bool needMask = (k0 + 63 > qw0);
            f32x4 s_acc[2][4];
            // ks = 0: C = zero quad (no per-tile acc init)
            {
                short8 kf[4];
#pragma unroll
                for (int ni = 0; ni < 4; ni++) {
                    const int key = ni * 16 + l;
                    const int c = key * 8 + (g ^ (key & 7));
                    kf[ni] = *(const short8*)&kb[c * 8];
                }
#pragma unroll
                for (int mi = 0; mi < 2; mi++)
#pragma unroll
                    for (int ni = 0; ni < 4; ni++)
                        s_acc[mi][ni] = __builtin_amdgcn_mfma_f32_16x16x32_bf16(
                            kf[ni], qf[mi][0], z4, 0, 0, 0);
            }
            // ks = 1: accumulate
            {
                short8 kf[4];
#pragma unroll
                for (int ni = 0; ni < 4; ni++) {
                    const int key = ni * 16 + l;
                    const int c = key * 8 + ((4 + g) ^ (key & 7));
                    kf[ni] = *(const short8*)&kb[c * 8];
                }
#pragma unroll
                for (int mi = 0; mi < 2; mi++)
#pragma unroll
                    for (int ni = 0; ni < 4; ni++)
                        s_acc[mi][ni] = __builtin_amdgcn_mfma_f32_16x16x32_bf16(
                            kf[ni], qf[mi][1], s_acc[mi][ni], 0, 0, 0);
            }
#pragma unroll
            for (int mi = 0; mi < 2; mi++) {
                const int qg = qw0 + mi * 16 + l;
#pragma unroll
                for (int ni = 0; ni < 4; ni++) {
                    const int keyb = k0 + ni * 16 + 4 * g;
                    s16x4 pv;
#pragma unroll
                    for (int r = 0; r < 4; r++) {
                        float s = s_acc[mi][ni][r];
                        if (needMask && (keyb + r > qg)) s = -1e30f;
                        float pe;
                        asm("v_exp_f32 %0, %1" : "=v"(pe) : "v"(s));  // pe = 2^s
                        pv[r] = f2s(pe);
                    }
                    *(s16x4*)(void*)&Pl[w][mi * 16 + l][ni * 16 + 4 * g] = pv;
                }
            }
#pragma unroll
            for (int ks = 0; ks < 2; ks++) {
                short8 pf[2], vf[4];
#pragma unroll
                for (int mi = 0; mi < 2; mi++)
                    pf[mi] = *(const short8*)&Pl[w][mi * 16 + l][ks * 32 + g * 8];
#pragma unroll
                for (int nd = 0; nd < 4; nd++) {
                    const int d = nd * 16 + l;
                    const int cb = ks * 4 + g;
                    vf[nd] = *(const short8*)&Vt[d][((cb ^ (d >> 3)) << 3)];
                }
#pragma unroll
                for (int mi = 0; mi < 2; mi++) {
                    l_acc[mi] = __builtin_amdgcn_mfma_f32_16x16x32_bf16(
                        pf[mi], onesf, l_acc[mi], 0, 0, 0);
#pragma unroll
                    for (int nd = 0; nd < 4; nd++)
                        o_acc[mi][nd] = __builtin_amdgcn_mfma_f32_16x16x32_bf16(
                            pf[mi], vf[nd], o_acc[mi][nd], 0, 0, 0);
                }
            }
        }
    }

#pragma unroll
    for (int mi = 0; mi < 2; mi++)
#pragma unroll
        for (int r = 0; r < 4; r++) {
            const float lsum = __shfl(l_acc[mi][r], lane & 48);
            const float inv = 1.0f / lsum;
            const int qg = qw0 + mi * 16 + 4 * g + r;
            short* op = (short*)(void*)(o + (rbase + qg) * 1024 + hcol);
#pragma unroll
            for (int nd = 0; nd < 4; nd++)
                op[nd * 16 + l] = f2s(o_acc[mi][nd][r] * inv);
        }
}

// ---------------- launch (round-10 configuration) ----------------
extern "C" void kernel_launch(void* const* d_in, const int* in_sizes, int n_in,
                              void* d_out, int out_size, void* d_ws, size_t ws_size,
                              hipStream_t stream) {
    const float* x   = (const float*)d_in[0];
    const float* Wq  = (const float*)d_in[1];
    const float* Wk  = (const float*)d_in[2];
    const float* Wv  = (const float*)d_in[3];
    const float* Wo  = (const float*)d_in[4];
    const float* bo  = (const float*)d_in[5];
    const float* W1  = (const float*)d_in[6];
    const float* b1  = (const float*)d_in[7];
    const float* W2  = (const float*)d_in[8];
    const float* b2  = (const float*)d_in[9];
    const float* g1  = (const float*)d_in[10];
    const float* be1 = (const float*)d_in[11];
    const float* g2  = (const float*)d_in[12];
    const float* be2 = (const float*)d_in[13];

    char* ws = (char*)d_ws;
    const size_t MB = (size_t)1024 * 1024;
    bf16*  s0  = (bf16*)(ws);               // h -> attn-out (16 MB)
    bf16*  qkv = (bf16*)(ws + 16 * MB);     // [8192][3072] bf16 (48 MB)
    short* WoT = (short*)(ws + 16 * MB);    // after attn (2 MB)
    short* W1T = (short*)(ws);              // after Wo GEMM: [4096][1024] (8 MB)
    short* W2T = (short*)(ws + 8 * MB);     // [1024][4096] (8 MB)
    bf16*  h2  = (bf16*)(ws + 16 * MB);     // after Wo GEMM (16 MB)
    bf16*  m1  = (bf16*)(ws + 32 * MB);     // MLP half intermediate (32 MB)
    short* WT  = (short*)d_out;             // QKV weightT scratch (6 MB, dies pre-x1)
    float* x1  = (float*)d_out;

    const int M = 8192, C = 1024, F = 4096, MH = 4096;

    tconv_kernel<<<dim3(16, 16), 256, 0, stream>>>(Wq, WT,                   C, C);
    tconv_kernel<<<dim3(16, 16), 256, 0, stream>>>(Wk, WT + 1024 * 1024,     C, C);
    tconv_kernel<<<dim3(16, 16), 256, 0, stream>>>(Wv, WT + 2 * 1024 * 1024, C, C);

    ln_kernel<<<M / 4, 256, 0, stream>>>(x, g1, be1, s0);

    // fused QKV: [8192][1024] @ [1024][3072] -> qkv bf16 (8-phase 256^2 core)
    gemm256<<<dim3(M / 256, 3072 / 256), 512, 0, stream>>>(
        s0, (const bf16*)WT, nullptr, qkv, 3072, 0);

    attn_kernel<<<dim3(64, 16), 256, 0, stream>>>(qkv, s0);

    // WoT into qkv region (dead); x1 = x + attn @ Wo + bo -> d_out fp32
    // Wo: 8192x1024 @ K=1024 -> gemm128 4-phase (512 blocks, 2/CU)
    tconv_kernel<<<dim3(16, 16), 256, 0, stream>>>(Wo, WoT, C, C);
    gemm128<<<dim3(M / 128, C / 128), 256, 0, stream>>>(
        s0, (const bf16*)WoT, bo, x, x1, 1, 0, C, C, 0);

    tconv_kernel<<<dim3(64, 16), 256, 0, stream>>>(W1, W1T, C, F);
    tconv_kernel<<<dim3(16, 64), 256, 0, stream>>>(W2, W2T, F, C);

    ln_kernel<<<M / 4, 256, 0, stream>>>(x1, g2, be2, h2);

    for (int half = 0; half < 2; half++) {
        const bf16* Ah = h2 + (size_t)half * MH * C;
        // W1: 4096x4096 @ K=1024 -> 256 blocks = 1/CU, 8-phase 256^2 core
        gemm256<<<dim3(MH / 256, F / 256), 512, 0, stream>>>(
            Ah, (const bf16*)W1T, b1, m1, F, 1);
        // W2: 4096x1024 @ K=4096 -> gemm128 4-phase (256 blocks, 2/CU, NT=64)
        gemm128<<<dim3(MH / 128, C / 128), 256, 0, stream>>>(
            m1, (const bf16*)W2T, b2, x1, d_out, 1, half * MH, C, F, 0);
    }
}

// Round 12
// 551.639 us; speedup vs baseline: 1.0500x; 1.0500x over previous
//
#include <hip/hip_runtime.h>
#include <hip/hip_bf16.h>

typedef __hip_bfloat16 bf16;
typedef __attribute__((ext_vector_type(8))) short short8;
typedef __attribute__((ext_vector_type(4))) short s16x4;
typedef __attribute__((ext_vector_type(4))) float f32x4;

__device__ __forceinline__ float s2f(short s) {
    unsigned u = ((unsigned)(unsigned short)s) << 16;
    return __builtin_bit_cast(float, u);
}
__device__ __forceinline__ short f2s(float f) {
    bf16 h = __float2bfloat16(f);
    return __builtin_bit_cast(short, h);
}
__device__ __forceinline__ void gload_lds16(const void* g, void* l) {
    __builtin_amdgcn_global_load_lds(
        (const __attribute__((address_space(1))) unsigned int*)g,
        (__attribute__((address_space(3))) unsigned int*)l, 16, 0, 0);
}

#define PH_VM8  asm volatile("s_waitcnt vmcnt(8)" ::: "memory")
#define PH_VM4  asm volatile("s_waitcnt vmcnt(4)" ::: "memory")
#define PH_VM0  asm volatile("s_waitcnt vmcnt(0)" ::: "memory")
#define PH_BAR  __builtin_amdgcn_s_barrier()
#define PH_LGKM do { asm volatile("s_waitcnt lgkmcnt(0)" ::: "memory"); \
                     __builtin_amdgcn_sched_barrier(0); } while (0)

// ---------------- convert+transpose: src fp32 [R][C] -> dst bf16 [C][R] ----------------
__global__ __launch_bounds__(256) void tconv_kernel(const float* __restrict__ src,
                                                    short* __restrict__ dst,
                                                    int R, int C) {
    __shared__ short tile[64][65];
    const int r0 = blockIdx.y * 64, c0 = blockIdx.x * 64;
    const int t = threadIdx.x;
    const int lr = t >> 2, lc = (t & 3) * 16;
    const float* sp = src + (size_t)(r0 + lr) * C + c0 + lc;
#pragma unroll
    for (int q = 0; q < 4; q++) {
        f32x4 v = *(const f32x4*)(const void*)(sp + q * 4);
#pragma unroll
        for (int j = 0; j < 4; j++) tile[lr][lc + q * 4 + j] = f2s(v[j]);
    }
    __syncthreads();
    short8 o0, o1;
#pragma unroll
    for (int j = 0; j < 8; j++) { o0[j] = tile[lc + j][lr]; o1[j] = tile[lc + 8 + j][lr]; }
    short* dp = dst + (size_t)(c0 + lr) * R + r0 + lc;
    *(short8*)(void*)dp = o0;
    *(short8*)(void*)(dp + 8) = o1;
}

// ---------------- LayerNorm: wave-per-row, 4 rows/block, fp32 in -> bf16 out ----------------
__global__ __launch_bounds__(256) void ln_kernel(const float* __restrict__ x,
                                                 const float* __restrict__ g,
                                                 const float* __restrict__ beta,
                                                 bf16* __restrict__ out) {
    const int t = threadIdx.x;
    const int w = t >> 6, lane = t & 63;
    const int row = blockIdx.x * 4 + w;
    const float* xr = x + (size_t)row * 1024;
    float v[16];
    float s = 0.f, ss = 0.f;
#pragma unroll
    for (int p = 0; p < 4; p++) {
        f32x4 xv = *(const f32x4*)(const void*)(xr + p * 256 + lane * 4);
#pragma unroll
        for (int j = 0; j < 4; j++) {
            v[p * 4 + j] = xv[j];
            s += xv[j];
            ss += xv[j] * xv[j];
        }
    }
#pragma unroll
    for (int off = 32; off >= 1; off >>= 1) {
        s += __shfl_xor(s, off);
        ss += __shfl_xor(ss, off);
    }
    const float mu = s * (1.0f / 1024.0f);
    const float var = ss * (1.0f / 1024.0f) - mu * mu;
    const float rstd = rsqrtf(var + 1e-5f);
    short* orow = (short*)(void*)(out + (size_t)row * 1024);
#pragma unroll
    for (int p = 0; p < 4; p++) {
        const int c = p * 256 + lane * 4;
        f32x4 gv = *(const f32x4*)(const void*)(g + c);
        f32x4 bv = *(const f32x4*)(const void*)(beta + c);
        s16x4 o;
#pragma unroll
        for (int j = 0; j < 4; j++)
            o[j] = f2s((v[p * 4 + j] - mu) * rstd * gv[j] + bv[j]);
        *(s16x4*)(void*)(orow + c) = o;
    }
}

// ---------------- GEMM 128x128, BK=64: 4-phase counted-vmcnt core (Wo, W2) ----------
// (round-10 proven)
#define MM_BLK2(ACC)                                                         \
    do {                                                                     \
        __builtin_amdgcn_s_setprio(1);                                       \
        _Pragma("unroll")                                                    \
        for (int mi_ = 0; mi_ < 2; mi_++)                                    \
            _Pragma("unroll")                                                \
            for (int ni_ = 0; ni_ < 4; ni_++)                                \
                ACC[mi_][ni_] = __builtin_amdgcn_mfma_f32_16x16x32_bf16(     \
                    af[mi_], bf[ni_], ACC[mi_][ni_], 0, 0, 0);               \
        __builtin_amdgcn_s_setprio(0);                                       \
    } while (0)

__global__ __launch_bounds__(256, 2) void gemm128(const bf16* __restrict__ A,
                                                  const bf16* __restrict__ Bt,
                                                  const float* __restrict__ bias,
                                                  const float* resid,
                                                  void* Cp, int c_f32,
                                                  int m_base, int N, int K,
                                                  int relu_flag) {
    __shared__ char lds[65536];
    const int NT = K >> 6;

    const int t = threadIdx.x;
    const int w = t >> 6, lane = t & 63;
    const int l = lane & 15, g = lane >> 4;
    const int m0 = blockIdx.x * 128, n0 = blockIdx.y * 128;
    const int wm = (w >> 1) * 64, wn = (w & 1) * 64;
    const int qx = (g ^ ((l >> 1) & 3)) * 16;
    const int qh8 = (((lane & 3) ^ ((lane >> 3) & 3)) * 8);
    const int srow = w * 32 + (lane >> 2);
    const short* Asrc = (const short*)A;
    const short* Bsrc = (const short*)Bt;

    f32x4 accL[2][4] = {};
    f32x4 accH[2][4] = {};
    short8 af[2], bf[4];

    auto stage = [&](int th, int j) {
        const int ks = j >> 1, mat = j & 1;
        char* slot = lds + ((th & 1) << 15) + (mat << 14) + (ks << 13);
        const short* mp = mat ? Bsrc : Asrc;
        const int rowb = (mat ? n0 : m0);
        const int kc = th * 64 + ks * 32 + qh8;
        gload_lds16(mp + (size_t)(rowb + srow) * K + kc,      slot + w * 2048);
        gload_lds16(mp + (size_t)(rowb + srow + 16) * K + kc, slot + w * 2048 + 1024);
    };
    auto lda_ = [&](const char* rb, int mi, int ks) -> short8 {
        return *(const short8*)(rb + (ks << 13) + (wm + mi * 16 + l) * 64 + qx);
    };
    auto ldb_ = [&](const char* rb, int ni, int ks) -> short8 {
        return *(const short8*)(rb + 16384 + (ks << 13) + (wn + ni * 16 + l) * 64 + qx);
    };

    stage(0, 0); stage(0, 1); stage(0, 2); stage(0, 3); stage(1, 0); stage(1, 1);

    for (int it = 0; it < NT - 1; ++it) {
        const char* rb = lds + ((it & 1) << 15);
        PH_VM8; PH_BAR;
        af[0] = lda_(rb, 0, 0); af[1] = lda_(rb, 1, 0);
#pragma unroll
        for (int i = 0; i < 4; i++) bf[i] = ldb_(rb, i, 0);
        stage(it + 1, 2);
        PH_LGKM;
        MM_BLK2(accL);
        af[0] = lda_(rb, 2, 0); af[1] = lda_(rb, 3, 0);
        stage(it + 1, 3);
        PH_BAR; PH_LGKM;
        MM_BLK2(accH);
        PH_VM8; PH_BAR;
        af[0] = lda_(rb, 0, 1); af[1] = lda_(rb, 1, 1);
#pragma unroll
        for (int i = 0; i < 4; i++) bf[i] = ldb_(rb, i, 1);
        if (it + 2 < NT) stage(it + 2, 0);
        PH_LGKM;
        MM_BLK2(accL);
        af[0] = lda_(rb, 2, 1); af[1] = lda_(rb, 3, 1);
        if (it + 2 < NT) stage(it + 2, 1);
        PH_BAR; PH_LGKM;
        MM_BLK2(accH);
    }
    {
        const char* rb = lds + (((NT - 1) & 1) << 15);
        PH_VM4; PH_BAR;
        af[0] = lda_(rb, 0, 0); af[1] = lda_(rb, 1, 0);
#pragma unroll
        for (int i = 0; i < 4; i++) bf[i] = ldb_(rb, i, 0);
        PH_LGKM;
        MM_BLK2(accL);
        af[0] = lda_(rb, 2, 0); af[1] = lda_(rb, 3, 0);
        PH_BAR; PH_LGKM;
        MM_BLK2(accH);
        PH_VM0; PH_BAR;
        af[0] = lda_(rb, 0, 1); af[1] = lda_(rb, 1, 1);
#pragma unroll
        for (int i = 0; i < 4; i++) bf[i] = ldb_(rb, i, 1);
        PH_LGKM;
        MM_BLK2(accL);
        af[0] = lda_(rb, 2, 1); af[1] = lda_(rb, 3, 1);
        PH_BAR; PH_LGKM;
        MM_BLK2(accH);
    }

#pragma unroll
    for (int half = 0; half < 2; half++)
#pragma unroll
        for (int mi = 0; mi < 2; mi++)
#pragma unroll
            for (int r = 0; r < 4; r++) {
                const int grow = m_base + m0 + wm + (half * 2 + mi) * 16 + g * 4 + r;
                const size_t rowoff = (size_t)grow * N;
#pragma unroll
                for (int ni = 0; ni < 4; ni++) {
                    const int gcol = n0 + wn + ni * 16 + l;
                    float val = half ? accH[mi][ni][r] : accL[mi][ni][r];
                    if (bias) val += bias[gcol];
                    if (relu_flag) val = fmaxf(val, 0.f);
                    const size_t ci = rowoff + gcol;
                    if (resid) val += resid[ci];
                    if (c_f32) ((float*)Cp)[ci] = val;
                    else       ((short*)Cp)[ci] = f2s(val);
                }
            }
}

// ---------------- GEMM 256x256, BK=64, K=1024 fixed: 8-phase counted-vmcnt core ----
// (round-4 exact — proven in r4/r6/r7/r9/r10)
#define MM_BLOCK(ACC)                                                        \
    do {                                                                     \
        __builtin_amdgcn_s_setprio(1);                                       \
        _Pragma("unroll")                                                    \
        for (int mi_ = 0; mi_ < 4; mi_++)                                    \
            _Pragma("unroll")                                                \
            for (int ni_ = 0; ni_ < 4; ni_++)                                \
                ACC[mi_][ni_] = __builtin_amdgcn_mfma_f32_16x16x32_bf16(     \
                    af[mi_], bf[ni_], ACC[mi_][ni_], 0, 0, 0);               \
        __builtin_amdgcn_s_setprio(0);                                       \
    } while (0)

__global__ __launch_bounds__(512, 2) void gemm256(const bf16* __restrict__ A,
                                                  const bf16* __restrict__ Bt,
                                                  const float* __restrict__ bias,
                                                  bf16* __restrict__ Cp,
                                                  int N, int relu_flag) {
    __shared__ char lds[131072];
    constexpr int NT = 16;   // K = 1024 = NT * 64

    const int t = threadIdx.x;
    const int w = t >> 6, lane = t & 63;
    const int l = lane & 15, g = lane >> 4;
    const int m0 = blockIdx.x * 256, n0 = blockIdx.y * 256;
    const int wm = (w >> 2) * 128, wn = (w & 3) * 64;
    const int qx = (g ^ ((l >> 1) & 3)) * 16;
    const int qh8 = (((lane & 3) ^ ((lane >> 3) & 3)) * 8);
    const int srow = w * 32 + (lane >> 2);
    const short* Asrc = (const short*)A;
    const short* Bsrc = (const short*)Bt;

    f32x4 accL[4][4] = {};
    f32x4 accH[4][4] = {};
    short8 af[4], bf[4];

    auto stage = [&](int th, int j) {
        const int ks = j >> 1, mat = j & 1;
        char* slot = lds + ((th & 1) << 16) + (mat << 15) + (ks << 14);
        const short* mp = mat ? Bsrc : Asrc;
        const int rowb = (mat ? n0 : m0);
        const int kc = th * 64 + ks * 32 + qh8;
        gload_lds16(mp + (size_t)(rowb + srow) * 1024 + kc,      slot + (w * 2) * 1024);
        gload_lds16(mp + (size_t)(rowb + srow + 16) * 1024 + kc, slot + (w * 2 + 1) * 1024);
    };
    auto lda = [&](const char* rb, int mi, int ks) -> short8 {
        return *(const short8*)(rb + (ks << 14) + (wm + mi * 16 + l) * 64 + qx);
    };
    auto ldb = [&](const char* rb, int ni, int ks) -> short8 {
        return *(const short8*)(rb + 32768 + (ks << 14) + (wn + ni * 16 + l) * 64 + qx);
    };

    stage(0, 0); stage(0, 1); stage(0, 2); stage(0, 3); stage(1, 0); stage(1, 1);

    for (int it = 0; it < NT - 1; ++it) {
        const char* rb = lds + ((it & 1) << 16);
        PH_VM8; PH_BAR;
#pragma unroll
        for (int i = 0; i < 4; i++) af[i] = lda(rb, i, 0);
#pragma unroll
        for (int i = 0; i < 4; i++) bf[i] = ldb(rb, i, 0);
        stage(it + 1, 2);
        PH_LGKM;
        MM_BLOCK(accL);
#pragma unroll
        for (int i = 0; i < 4; i++) af[i] = lda(rb, 4 + i, 0);
        stage(it + 1, 3);
        PH_BAR; PH_LGKM;
        MM_BLOCK(accH);
        PH_VM8; PH_BAR;
#pragma unroll
        for (int i = 0; i < 4; i++) af[i] = lda(rb, i, 1);
#pragma unroll
        for (int i = 0; i < 4; i++) bf[i] = ldb(rb, i, 1);
        if (it + 2 < NT) stage(it + 2, 0);
        PH_LGKM;
        MM_BLOCK(accL);
#pragma unroll
        for (int i = 0; i < 4; i++) af[i] = lda(rb, 4 + i, 1);
        if (it + 2 < NT) stage(it + 2, 1);
        PH_BAR; PH_LGKM;
        MM_BLOCK(accH);
    }
    {
        const char* rb = lds + (((NT - 1) & 1) << 16);
        PH_VM4; PH_BAR;
#pragma unroll
        for (int i = 0; i < 4; i++) af[i] = lda(rb, i, 0);
#pragma unroll
        for (int i = 0; i < 4; i++) bf[i] = ldb(rb, i, 0);
        PH_LGKM;
        MM_BLOCK(accL);
#pragma unroll
        for (int i = 0; i < 4; i++) af[i] = lda(rb, 4 + i, 0);
        PH_BAR; PH_LGKM;
        MM_BLOCK(accH);
        PH_VM0; PH_BAR;
#pragma unroll
        for (int i = 0; i < 4; i++) af[i] = lda(rb, i, 1);
#pragma unroll
        for (int i = 0; i < 4; i++) bf[i] = ldb(rb, i, 1);
        PH_LGKM;
        MM_BLOCK(accL);
#pragma unroll
        for (int i = 0; i < 4; i++) af[i] = lda(rb, 4 + i, 1);
        PH_BAR; PH_LGKM;
        MM_BLOCK(accH);
    }

#pragma unroll
    for (int half = 0; half < 2; half++)
#pragma unroll
        for (int mi = 0; mi < 4; mi++)
#pragma unroll
            for (int r = 0; r < 4; r++) {
                const int grow = m0 + wm + (half * 4 + mi) * 16 + g * 4 + r;
                short* crow = (short*)(void*)Cp + (size_t)grow * N;
#pragma unroll
                for (int ni = 0; ni < 4; ni++) {
                    const int gcol = n0 + wn + ni * 16 + l;
                    float val = half ? accH[mi][ni][r] : accL[mi][ni][r];
                    if (bias) val += bias[gcol];
                    if (relu_flag) val = fmaxf(val, 0.f);
                    crow[gcol] = f2s(val);
                }
            }
}

// ---------------- MFMA flash attention: swapped QK^T + exp-fold (keep r10 l_sum) ----
// vs r10 (73.4us proven): ONLY (1) exp scale folded into qf (0.125*log2e) ->
// raw v_exp_f32 (2^s), no per-element mul [r11-verified correct]; (2) s_acc
// zero-init via MFMA C operand (shift cancels in O = PV/l) — both
// register-neutral. r11's ones-MFMA row-sum REVERTED (cost occupancy:
// 84->88 VGPR, 26.5->19%): lane-local l_sum restored.
__global__ __launch_bounds__(256) void attn_kernel(const bf16* __restrict__ qkv,
                                                   bf16* __restrict__ o) {
    __shared__ short KsF[2][4096];
    __shared__ short Vt[64][72];
    __shared__ short Pl[4][32][76];

    const int bh = blockIdx.x;
    const int b = bh >> 4, h = bh & 15;
    const int qt = 15 - blockIdx.y;
    const int q0 = qt * 128;
    const size_t rbase = (size_t)b * 2048;
    const int hcol = h * 64;

    const int t = threadIdx.x;
    const int w = t >> 6;
    const int lane = t & 63;
    const int l = lane & 15;
    const int g = lane >> 4;
    const int sp = t >> 3;
    const int sb = (t & 7) * 8;

    const int qw0 = q0 + 32 * w;
    short8 qf[2][2];
#pragma unroll
    for (int mi = 0; mi < 2; mi++)
#pragma unroll
        for (int ks = 0; ks < 2; ks++) {
            const short* qp = (const short*)qkv +
                (rbase + qw0 + mi * 16 + l) * 3072 + hcol + ks * 32 + g * 8;
            short8 tv = *(const short8*)(const void*)qp;
            short8 sv;
#pragma unroll
            for (int e = 0; e < 8; e++) sv[e] = f2s(s2f(tv[e]) * 0.18033688f); // 0.125*log2(e)
            qf[mi][ks] = sv;
        }

    const int key_a = w * 16 + (lane >> 3);
    const int kd = (lane & 7) ^ ((lane >> 3) & 7);
    const short* kgA = (const short*)qkv + (rbase + key_a) * 3072 + 1024 + hcol + kd * 8;
    const short* kgB = kgA + 8 * 3072;

    f32x4 o_acc[2][4] = {};
    float l_sum[2] = {0.f, 0.f};
    const f32x4 z4 = {0.f, 0.f, 0.f, 0.f};

    const int kt_max = (q0 + 127) >> 6;

    gload_lds16(kgA, &KsF[0][w * 1024]);
    gload_lds16(kgB, &KsF[0][w * 1024 + 512]);

    for (int kt = 0; kt <= kt_max; kt++) {
        const int k0 = kt * 64;
        const short* vg = (const short*)qkv + (rbase + k0 + 2 * sp) * 3072 + 2048 + hcol + sb;
        short8 vv0 = *(const short8*)(const void*)vg;
        short8 vv1 = *(const short8*)(const void*)(vg + 3072);
        PH_BAR;
        {
            const int kp = (kt < kt_max) ? (kt + 1) : kt;
            const size_t kof = (size_t)kp * 64 * 3072;
            gload_lds16(kgA + kof, &KsF[(kt + 1) & 1][w * 1024]);
            gload_lds16(kgB + kof, &KsF[(kt + 1) & 1][w * 1024 + 512]);
        }
        asm volatile("s_waitcnt vmcnt(2)" ::: "memory");
        __builtin_amdgcn_sched_barrier(0);
        {
            const int key = 2 * sp;
            const int cbk = key >> 3;
            const int kin = key & 7;
#pragma unroll
            for (int j = 0; j < 8; j++) {
                const int d = sb + j;
                const int col = ((cbk ^ (d >> 3)) << 3) + kin;
                int pk = (int)(unsigned short)vv0[j] | ((int)(unsigned short)vv1[j] << 16);
                *(int*)(void*)&Vt[d][col] = pk;
            }
        }
        asm volatile("s_waitcnt lgkmcnt(0)" ::: "memory");
        __builtin_amdgcn_sched_barrier(0);
        PH_BAR;

        if (k0 <= qw0 + 31) {
            const short* kb = &KsF[kt & 1][0];
            const bool needMask = (k0 + 63 > qw0);
            f32x4 s_acc[2][4];
            // ks = 0: C = zero quad (no per-tile acc init)
            {
                short8 kf[4];
#pragma unroll
                for (int ni = 0; ni < 4; ni++) {
                    const int key = ni * 16 + l;
                    const int c = key * 8 + (g ^ (key & 7));
                    kf[ni] = *(const short8*)&kb[c * 8];
                }
#pragma unroll
                for (int mi = 0; mi < 2; mi++)
#pragma unroll
                    for (int ni = 0; ni < 4; ni++)
                        s_acc[mi][ni] = __builtin_amdgcn_mfma_f32_16x16x32_bf16(
                            kf[ni], qf[mi][0], z4, 0, 0, 0);
            }
            // ks = 1: accumulate
            {
                short8 kf[4];
#pragma unroll
                for (int ni = 0; ni < 4; ni++) {
                    const int key = ni * 16 + l;
                    const int c = key * 8 + ((4 + g) ^ (key & 7));
                    kf[ni] = *(const short8*)&kb[c * 8];
                }
#pragma unroll
                for (int mi = 0; mi < 2; mi++)
#pragma unroll
                    for (int ni = 0; ni < 4; ni++)
                        s_acc[mi][ni] = __builtin_amdgcn_mfma_f32_16x16x32_bf16(
                            kf[ni], qf[mi][1], s_acc[mi][ni], 0, 0, 0);
            }
#pragma unroll
            for (int mi = 0; mi < 2; mi++) {
                const int qg = qw0 + mi * 16 + l;
#pragma unroll
                for (int ni = 0; ni < 4; ni++) {
                    const int keyb = k0 + ni * 16 + 4 * g;
                    s16x4 pv;
#pragma unroll
                    for (int r = 0; r < 4; r++) {
                        float s = s_acc[mi][ni][r];
                        if (needMask && (keyb + r > qg)) s = -1e30f;
                        float pe;
                        asm("v_exp_f32 %0, %1" : "=v"(pe) : "v"(s));  // pe = 2^s
                        l_sum[mi] += pe;
                        pv[r] = f2s(pe);
                    }
                    *(s16x4*)(void*)&Pl[w][mi * 16 + l][ni * 16 + 4 * g] = pv;
                }
            }
#pragma unroll
            for (int ks = 0; ks < 2; ks++) {
                short8 pf[2], vf[4];
#pragma unroll
                for (int mi = 0; mi < 2; mi++)
                    pf[mi] = *(const short8*)&Pl[w][mi * 16 + l][ks * 32 + g * 8];
#pragma unroll
                for (int nd = 0; nd < 4; nd++) {
                    const int d = nd * 16 + l;
                    const int cb = ks * 4 + g;
                    vf[nd] = *(const short8*)&Vt[d][((cb ^ (d >> 3)) << 3)];
                }
#pragma unroll
                for (int mi = 0; mi < 2; mi++)
#pragma unroll
                    for (int nd = 0; nd < 4; nd++)
                        o_acc[mi][nd] = __builtin_amdgcn_mfma_f32_16x16x32_bf16(
                            pf[mi], vf[nd], o_acc[mi][nd], 0, 0, 0);
            }
        }
    }

#pragma unroll
    for (int mi = 0; mi < 2; mi++) {
        l_sum[mi] += __shfl_xor(l_sum[mi], 16);
        l_sum[mi] += __shfl_xor(l_sum[mi], 32);
    }

#pragma unroll
    for (int mi = 0; mi < 2; mi++)
#pragma unroll
        for (int r = 0; r < 4; r++) {
            const float lsum = __shfl(l_sum[mi], 4 * g + r);
            const float inv = 1.0f / lsum;
            const int qg = qw0 + mi * 16 + 4 * g + r;
            short* op = (short*)(void*)(o + (rbase + qg) * 1024 + hcol);
#pragma unroll
            for (int nd = 0; nd < 4; nd++)
                op[nd * 16 + l] = f2s(o_acc[mi][nd][r] * inv);
        }
}

// ---------------- launch (round-10 configuration) ----------------
extern "C" void kernel_launch(void* const* d_in, const int* in_sizes, int n_in,
                              void* d_out, int out_size, void* d_ws, size_t ws_size,
                              hipStream_t stream) {
    const float* x   = (const float*)d_in[0];
    const float* Wq  = (const float*)d_in[1];
    const float* Wk  = (const float*)d_in[2];
    const float* Wv  = (const float*)d_in[3];
    const float* Wo  = (const float*)d_in[4];
    const float* bo  = (const float*)d_in[5];
    const float* W1  = (const float*)d_in[6];
    const float* b1  = (const float*)d_in[7];
    const float* W2  = (const float*)d_in[8];
    const float* b2  = (const float*)d_in[9];
    const float* g1  = (const float*)d_in[10];
    const float* be1 = (const float*)d_in[11];
    const float* g2  = (const float*)d_in[12];
    const float* be2 = (const float*)d_in[13];

    char* ws = (char*)d_ws;
    const size_t MB = (size_t)1024 * 1024;
    bf16*  s0  = (bf16*)(ws);               // h -> attn-out (16 MB)
    bf16*  qkv = (bf16*)(ws + 16 * MB);     // [8192][3072] bf16 (48 MB)
    short* WoT = (short*)(ws + 16 * MB);    // after attn (2 MB)
    short* W1T = (short*)(ws);              // after Wo GEMM: [4096][1024] (8 MB)
    short* W2T = (short*)(ws + 8 * MB);     // [1024][4096] (8 MB)
    bf16*  h2  = (bf16*)(ws + 16 * MB);     // after Wo GEMM (16 MB)
    bf16*  m1  = (bf16*)(ws + 32 * MB);     // MLP half intermediate (32 MB)
    short* WT  = (short*)d_out;             // QKV weightT scratch (6 MB, dies pre-x1)
    float* x1  = (float*)d_out;

    const int M = 8192, C = 1024, F = 4096, MH = 4096;

    tconv_kernel<<<dim3(16, 16), 256, 0, stream>>>(Wq, WT,                   C, C);
    tconv_kernel<<<dim3(16, 16), 256, 0, stream>>>(Wk, WT + 1024 * 1024,     C, C);
    tconv_kernel<<<dim3(16, 16), 256, 0, stream>>>(Wv, WT + 2 * 1024 * 1024, C, C);

    ln_kernel<<<M / 4, 256, 0, stream>>>(x, g1, be1, s0);

    // fused QKV: [8192][1024] @ [1024][3072] -> qkv bf16 (8-phase 256^2 core)
    gemm256<<<dim3(M / 256, 3072 / 256), 512, 0, stream>>>(
        s0, (const bf16*)WT, nullptr, qkv, 3072, 0);

    attn_kernel<<<dim3(64, 16), 256, 0, stream>>>(qkv, s0);

    // WoT into qkv region (dead); x1 = x + attn @ Wo + bo -> d_out fp32
    // Wo: 8192x1024 @ K=1024 -> gemm128 4-phase (512 blocks, 2/CU)
    tconv_kernel<<<dim3(16, 16), 256, 0, stream>>>(Wo, WoT, C, C);
    gemm128<<<dim3(M / 128, C / 128), 256, 0, stream>>>(
        s0, (const bf16*)WoT, bo, x, x1, 1, 0, C, C, 0);

    tconv_kernel<<<dim3(64, 16), 256, 0, stream>>>(W1, W1T, C, F);
    tconv_kernel<<<dim3(16, 64), 256, 0, stream>>>(W2, W2T, F, C);

    ln_kernel<<<M / 4, 256, 0, stream>>>(x1, g2, be2, h2);

    for (int half = 0; half < 2; half++) {
        const bf16* Ah = h2 + (size_t)half * MH * C;
        // W1: 4096x4096 @ K=1024 -> 256 blocks = 1/CU, 8-phase 256^2 core
        gemm256<<<dim3(MH / 256, F / 256), 512, 0, stream>>>(
            Ah, (const bf16*)W1T, b1, m1, F, 1);
        // W2: 4096x1024 @ K=4096 -> gemm128 4-phase (256 blocks, 2/CU, NT=64)
        gemm128<<<dim3(MH / 128, C / 128), 256, 0, stream>>>(
            m1, (const bf16*)W2T, b2, x1, d_out, 1, half * MH, C, F, 0);
    }
}

// Round 14
// 541.215 us; speedup vs baseline: 1.0702x; 1.0193x over previous
//
#include <hip/hip_runtime.h>
#include <hip/hip_bf16.h>

typedef __hip_bfloat16 bf16;
typedef __attribute__((ext_vector_type(8))) short short8;
typedef __attribute__((ext_vector_type(4))) short s16x4;
typedef __attribute__((ext_vector_type(4))) float f32x4;

__device__ __forceinline__ float s2f(short s) {
    unsigned u = ((unsigned)(unsigned short)s) << 16;
    return __builtin_bit_cast(float, u);
}
__device__ __forceinline__ short f2s(float f) {
    bf16 h = __float2bfloat16(f);
    return __builtin_bit_cast(short, h);
}
__device__ __forceinline__ void gload_lds16(const void* g, void* l) {
    __builtin_amdgcn_global_load_lds(
        (const __attribute__((address_space(1))) unsigned int*)g,
        (__attribute__((address_space(3))) unsigned int*)l, 16, 0, 0);
}

#define PH_VM8  asm volatile("s_waitcnt vmcnt(8)" ::: "memory")
#define PH_VM6  asm volatile("s_waitcnt vmcnt(6)" ::: "memory")
#define PH_VM4  asm volatile("s_waitcnt vmcnt(4)" ::: "memory")
#define PH_VM3  asm volatile("s_waitcnt vmcnt(3)" ::: "memory")
#define PH_VM0  asm volatile("s_waitcnt vmcnt(0)" ::: "memory")
#define PH_BAR  __builtin_amdgcn_s_barrier()
#define PH_LGKM do { asm volatile("s_waitcnt lgkmcnt(0)" ::: "memory"); \
                     __builtin_amdgcn_sched_barrier(0); } while (0)

// ---------------- convert+transpose: src fp32 [R][C] -> dst bf16 [C][R] ----------------
__global__ __launch_bounds__(256) void tconv_kernel(const float* __restrict__ src,
                                                    short* __restrict__ dst,
                                                    int R, int C) {
    __shared__ short tile[64][65];
    const int r0 = blockIdx.y * 64, c0 = blockIdx.x * 64;
    const int t = threadIdx.x;
    const int lr = t >> 2, lc = (t & 3) * 16;
    const float* sp = src + (size_t)(r0 + lr) * C + c0 + lc;
#pragma unroll
    for (int q = 0; q < 4; q++) {
        f32x4 v = *(const f32x4*)(const void*)(sp + q * 4);
#pragma unroll
        for (int j = 0; j < 4; j++) tile[lr][lc + q * 4 + j] = f2s(v[j]);
    }
    __syncthreads();
    short8 o0, o1;
#pragma unroll
    for (int j = 0; j < 8; j++) { o0[j] = tile[lc + j][lr]; o1[j] = tile[lc + 8 + j][lr]; }
    short* dp = dst + (size_t)(c0 + lr) * R + r0 + lc;
    *(short8*)(void*)dp = o0;
    *(short8*)(void*)(dp + 8) = o1;
}

// ---------------- LayerNorm: wave-per-row, 4 rows/block, fp32 in -> bf16 out ----------------
__global__ __launch_bounds__(256) void ln_kernel(const float* __restrict__ x,
                                                 const float* __restrict__ g,
                                                 const float* __restrict__ beta,
                                                 bf16* __restrict__ out) {
    const int t = threadIdx.x;
    const int w = t >> 6, lane = t & 63;
    const int row = blockIdx.x * 4 + w;
    const float* xr = x + (size_t)row * 1024;
    float v[16];
    float s = 0.f, ss = 0.f;
#pragma unroll
    for (int p = 0; p < 4; p++) {
        f32x4 xv = *(const f32x4*)(const void*)(xr + p * 256 + lane * 4);
#pragma unroll
        for (int j = 0; j < 4; j++) {
            v[p * 4 + j] = xv[j];
            s += xv[j];
            ss += xv[j] * xv[j];
        }
    }
#pragma unroll
    for (int off = 32; off >= 1; off >>= 1) {
        s += __shfl_xor(s, off);
        ss += __shfl_xor(ss, off);
    }
    const float mu = s * (1.0f / 1024.0f);
    const float var = ss * (1.0f / 1024.0f) - mu * mu;
    const float rstd = rsqrtf(var + 1e-5f);
    short* orow = (short*)(void*)(out + (size_t)row * 1024);
#pragma unroll
    for (int p = 0; p < 4; p++) {
        const int c = p * 256 + lane * 4;
        f32x4 gv = *(const f32x4*)(const void*)(g + c);
        f32x4 bv = *(const f32x4*)(const void*)(beta + c);
        s16x4 o;
#pragma unroll
        for (int j = 0; j < 4; j++)
            o[j] = f2s((v[p * 4 + j] - mu) * rstd * gv[j] + bv[j]);
        *(s16x4*)(void*)(orow + c) = o;
    }
}

// ---------------- GEMM 128x128, BK=64: 4-phase counted-vmcnt core (Wo) ----------
// (round-10 proven)
#define MM_BLK2(ACC)                                                         \
    do {                                                                     \
        __builtin_amdgcn_s_setprio(1);                                       \
        _Pragma("unroll")                                                    \
        for (int mi_ = 0; mi_ < 2; mi_++)                                    \
            _Pragma("unroll")                                                \
            for (int ni_ = 0; ni_ < 4; ni_++)                                \
                ACC[mi_][ni_] = __builtin_amdgcn_mfma_f32_16x16x32_bf16(     \
                    af[mi_], bf[ni_], ACC[mi_][ni_], 0, 0, 0);               \
        __builtin_amdgcn_s_setprio(0);                                       \
    } while (0)

__global__ __launch_bounds__(256, 2) void gemm128(const bf16* __restrict__ A,
                                                  const bf16* __restrict__ Bt,
                                                  const float* __restrict__ bias,
                                                  const float* resid,
                                                  void* Cp, int c_f32,
                                                  int m_base, int N, int K,
                                                  int relu_flag) {
    __shared__ char lds[65536];
    const int NT = K >> 6;

    const int t = threadIdx.x;
    const int w = t >> 6, lane = t & 63;
    const int l = lane & 15, g = lane >> 4;
    const int m0 = blockIdx.x * 128, n0 = blockIdx.y * 128;
    const int wm = (w >> 1) * 64, wn = (w & 1) * 64;
    const int qx = (g ^ ((l >> 1) & 3)) * 16;
    const int qh8 = (((lane & 3) ^ ((lane >> 3) & 3)) * 8);
    const int srow = w * 32 + (lane >> 2);
    const short* Asrc = (const short*)A;
    const short* Bsrc = (const short*)Bt;

    f32x4 accL[2][4] = {};
    f32x4 accH[2][4] = {};
    short8 af[2], bf[4];

    auto stage = [&](int th, int j) {
        const int ks = j >> 1, mat = j & 1;
        char* slot = lds + ((th & 1) << 15) + (mat << 14) + (ks << 13);
        const short* mp = mat ? Bsrc : Asrc;
        const int rowb = (mat ? n0 : m0);
        const int kc = th * 64 + ks * 32 + qh8;
        gload_lds16(mp + (size_t)(rowb + srow) * K + kc,      slot + w * 2048);
        gload_lds16(mp + (size_t)(rowb + srow + 16) * K + kc, slot + w * 2048 + 1024);
    };
    auto lda_ = [&](const char* rb, int mi, int ks) -> short8 {
        return *(const short8*)(rb + (ks << 13) + (wm + mi * 16 + l) * 64 + qx);
    };
    auto ldb_ = [&](const char* rb, int ni, int ks) -> short8 {
        return *(const short8*)(rb + 16384 + (ks << 13) + (wn + ni * 16 + l) * 64 + qx);
    };

    stage(0, 0); stage(0, 1); stage(0, 2); stage(0, 3); stage(1, 0); stage(1, 1);

    for (int it = 0; it < NT - 1; ++it) {
        const char* rb = lds + ((it & 1) << 15);
        PH_VM8; PH_BAR;
        af[0] = lda_(rb, 0, 0); af[1] = lda_(rb, 1, 0);
#pragma unroll
        for (int i = 0; i < 4; i++) bf[i] = ldb_(rb, i, 0);
        stage(it + 1, 2);
        PH_LGKM;
        MM_BLK2(accL);
        af[0] = lda_(rb, 2, 0); af[1] = lda_(rb, 3, 0);
        stage(it + 1, 3);
        PH_BAR; PH_LGKM;
        MM_BLK2(accH);
        PH_VM8; PH_BAR;
        af[0] = lda_(rb, 0, 1); af[1] = lda_(rb, 1, 1);
#pragma unroll
        for (int i = 0; i < 4; i++) bf[i] = ldb_(rb, i, 1);
        if (it + 2 < NT) stage(it + 2, 0);
        PH_LGKM;
        MM_BLK2(accL);
        af[0] = lda_(rb, 2, 1); af[1] = lda_(rb, 3, 1);
        if (it + 2 < NT) stage(it + 2, 1);
        PH_BAR; PH_LGKM;
        MM_BLK2(accH);
    }
    {
        const char* rb = lds + (((NT - 1) & 1) << 15);
        PH_VM4; PH_BAR;
        af[0] = lda_(rb, 0, 0); af[1] = lda_(rb, 1, 0);
#pragma unroll
        for (int i = 0; i < 4; i++) bf[i] = ldb_(rb, i, 0);
        PH_LGKM;
        MM_BLK2(accL);
        af[0] = lda_(rb, 2, 0); af[1] = lda_(rb, 3, 0);
        PH_BAR; PH_LGKM;
        MM_BLK2(accH);
        PH_VM0; PH_BAR;
        af[0] = lda_(rb, 0, 1); af[1] = lda_(rb, 1, 1);
#pragma unroll
        for (int i = 0; i < 4; i++) bf[i] = ldb_(rb, i, 1);
        PH_LGKM;
        MM_BLK2(accL);
        af[0] = lda_(rb, 2, 1); af[1] = lda_(rb, 3, 1);
        PH_BAR; PH_LGKM;
        MM_BLK2(accH);
    }

#pragma unroll
    for (int half = 0; half < 2; half++)
#pragma unroll
        for (int mi = 0; mi < 2; mi++)
#pragma unroll
            for (int r = 0; r < 4; r++) {
                const int grow = m_base + m0 + wm + (half * 2 + mi) * 16 + g * 4 + r;
                const size_t rowoff = (size_t)grow * N;
#pragma unroll
                for (int ni = 0; ni < 4; ni++) {
                    const int gcol = n0 + wn + ni * 16 + l;
                    float val = half ? accH[mi][ni][r] : accL[mi][ni][r];
                    if (bias) val += bias[gcol];
                    if (relu_flag) val = fmaxf(val, 0.f);
                    const size_t ci = rowoff + gcol;
                    if (resid) val += resid[ci];
                    if (c_f32) ((float*)Cp)[ci] = val;
                    else       ((short*)Cp)[ci] = f2s(val);
                }
            }
}

// ---------------- GEMM 128x64, BK=64: 4-phase counted-vmcnt, narrow-N (W2) ----------
// RETRY of r13 (failed twice; exhaustive audit found no fault — ledger exact,
// barrier-ordering identical to proven gemm128, swizzle verified, bounds ok).
// r3 precedent: harness failed twice on a near-correct kernel, resubmit passed.
// Third strike condemns this kernel permanently.
// Ledger: prologue 9; lp0/lp2 vmcnt(6) retire oldest 3 (A=2,B=1 per half);
// peel 6 -> vmcnt(3) -> vmcnt(0). LDS 48KB; W2 grid 512 = 2 blocks/CU.
#define MM_BLKN(ACC)                                                         \
    do {                                                                     \
        __builtin_amdgcn_s_setprio(1);                                       \
        _Pragma("unroll")                                                    \
        for (int mi_ = 0; mi_ < 2; mi_++)                                    \
            _Pragma("unroll")                                                \
            for (int ni_ = 0; ni_ < 2; ni_++)                                \
                ACC[mi_][ni_] = __builtin_amdgcn_mfma_f32_16x16x32_bf16(     \
                    af[mi_], bf[ni_], ACC[mi_][ni_], 0, 0, 0);               \
        __builtin_amdgcn_s_setprio(0);                                       \
    } while (0)

__global__ __launch_bounds__(256, 2) void gemm128n64(const bf16* __restrict__ A,
                                                     const bf16* __restrict__ Bt,
                                                     const float* __restrict__ bias,
                                                     const float* resid,
                                                     void* Cp, int c_f32,
                                                     int m_base, int N, int K,
                                                     int relu_flag) {
    __shared__ char lds[49152];      // 2 x 24KB: A.ks0 8K | A.ks1 8K | B.ks0 4K | B.ks1 4K
    const int NT = K >> 6;

    const int t = threadIdx.x;
    const int w = t >> 6, lane = t & 63;
    const int l = lane & 15, g = lane >> 4;
    const int m0 = blockIdx.x * 128, n0 = blockIdx.y * 64;
    const int wm = (w >> 1) * 64, wn = (w & 1) * 32;
    const int qx = (g ^ ((l >> 1) & 3)) * 16;
    const int qh8 = (((lane & 3) ^ ((lane >> 3) & 3)) * 8);
    const int srow = w * 32 + (lane >> 2);      // A staging rows (2 gloads: +0, +16)
    const int srowB = w * 16 + (lane >> 2);     // B staging rows (1 gload)
    const short* Asrc = (const short*)A;
    const short* Bsrc = (const short*)Bt;

    f32x4 accL[2][2] = {};
    f32x4 accH[2][2] = {};
    short8 af[2], bf[2];

    auto stageA = [&](int th, int ks) {
        char* slot = lds + (th & 1) * 24576 + ks * 8192;
        const int kc = th * 64 + ks * 32 + qh8;
        gload_lds16(Asrc + (size_t)(m0 + srow) * K + kc,      slot + w * 2048);
        gload_lds16(Asrc + (size_t)(m0 + srow + 16) * K + kc, slot + w * 2048 + 1024);
    };
    auto stageB = [&](int th, int ks) {
        char* slot = lds + (th & 1) * 24576 + 16384 + ks * 4096;
        const int kc = th * 64 + ks * 32 + qh8;
        gload_lds16(Bsrc + (size_t)(n0 + srowB) * K + kc, slot + w * 1024);
    };
    auto lda_ = [&](const char* rb, int mi, int ks) -> short8 {
        return *(const short8*)(rb + ks * 8192 + (wm + mi * 16 + l) * 64 + qx);
    };
    auto ldb_ = [&](const char* rb, int ni, int ks) -> short8 {
        return *(const short8*)(rb + 16384 + ks * 4096 + (wn + ni * 16 + l) * 64 + qx);
    };

    // prologue: t0{A0(2),B0(1),A1(2),B1(1)}, t1{A0(2),B0(1)} -> 9 outstanding
    stageA(0, 0); stageB(0, 0); stageA(0, 1); stageB(0, 1); stageA(1, 0); stageB(1, 0);

    for (int it = 0; it < NT - 1; ++it) {
        const char* rb = lds + (it & 1) * 24576;
        // lp0: ks0, m-lo  (needs t_it A0+B0 = oldest 3)
        PH_VM6; PH_BAR;
        af[0] = lda_(rb, 0, 0); af[1] = lda_(rb, 1, 0);
        bf[0] = ldb_(rb, 0, 0); bf[1] = ldb_(rb, 1, 0);
        stageA(it + 1, 1);
        PH_LGKM;
        MM_BLKN(accL);
        // lp1: ks0, m-hi
        af[0] = lda_(rb, 2, 0); af[1] = lda_(rb, 3, 0);
        stageB(it + 1, 1);
        PH_BAR; PH_LGKM;
        MM_BLKN(accH);
        // lp2: ks1, m-lo  (needs t_it A1+B1 = oldest 3)
        PH_VM6; PH_BAR;
        af[0] = lda_(rb, 0, 1); af[1] = lda_(rb, 1, 1);
        bf[0] = ldb_(rb, 0, 1); bf[1] = ldb_(rb, 1, 1);
        if (it + 2 < NT) stageA(it + 2, 0);
        PH_LGKM;
        MM_BLKN(accL);
        // lp3: ks1, m-hi
        af[0] = lda_(rb, 2, 1); af[1] = lda_(rb, 3, 1);
        if (it + 2 < NT) stageB(it + 2, 0);
        PH_BAR; PH_LGKM;
        MM_BLKN(accH);
    }
    // peel: outstanding 6 (t_last A0,B0,A1,B1)
    {
        const char* rb = lds + ((NT - 1) & 1) * 24576;
        PH_VM3; PH_BAR;
        af[0] = lda_(rb, 0, 0); af[1] = lda_(rb, 1, 0);
        bf[0] = ldb_(rb, 0, 0); bf[1] = ldb_(rb, 1, 0);
        PH_LGKM;
        MM_BLKN(accL);
        af[0] = lda_(rb, 2, 0); af[1] = lda_(rb, 3, 0);
        PH_BAR; PH_LGKM;
        MM_BLKN(accH);
        PH_VM0; PH_BAR;
        af[0] = lda_(rb, 0, 1); af[1] = lda_(rb, 1, 1);
        bf[0] = ldb_(rb, 0, 1); bf[1] = ldb_(rb, 1, 1);
        PH_LGKM;
        MM_BLKN(accL);
        af[0] = lda_(rb, 2, 1); af[1] = lda_(rb, 3, 1);
        PH_BAR; PH_LGKM;
        MM_BLKN(accH);
    }

#pragma unroll
    for (int half = 0; half < 2; half++)
#pragma unroll
        for (int mi = 0; mi < 2; mi++)
#pragma unroll
            for (int r = 0; r < 4; r++) {
                const int grow = m_base + m0 + wm + (half * 2 + mi) * 16 + g * 4 + r;
                const size_t rowoff = (size_t)grow * N;
#pragma unroll
                for (int ni = 0; ni < 2; ni++) {
                    const int gcol = n0 + wn + ni * 16 + l;
                    float val = half ? accH[mi][ni][r] : accL[mi][ni][r];
                    if (bias) val += bias[gcol];
                    if (relu_flag) val = fmaxf(val, 0.f);
                    const size_t ci = rowoff + gcol;
                    if (resid) val += resid[ci];
                    if (c_f32) ((float*)Cp)[ci] = val;
                    else       ((short*)Cp)[ci] = f2s(val);
                }
            }
}

// ---------------- GEMM 256x256, BK=64, K=1024 fixed: 8-phase counted-vmcnt core ----
// (round-4 exact — proven in r4/r6/r7/r9/r10/r12)
#define MM_BLOCK(ACC)                                                        \
    do {                                                                     \
        __builtin_amdgcn_s_setprio(1);                                       \
        _Pragma("unroll")                                                    \
        for (int mi_ = 0; mi_ < 4; mi_++)                                    \
            _Pragma("unroll")                                                \
            for (int ni_ = 0; ni_ < 4; ni_++)                                \
                ACC[mi_][ni_] = __builtin_amdgcn_mfma_f32_16x16x32_bf16(     \
                    af[mi_], bf[ni_], ACC[mi_][ni_], 0, 0, 0);               \
        __builtin_amdgcn_s_setprio(0);                                       \
    } while (0)

__global__ __launch_bounds__(512, 2) void gemm256(const bf16* __restrict__ A,
                                                  const bf16* __restrict__ Bt,
                                                  const float* __restrict__ bias,
                                                  bf16* __restrict__ Cp,
                                                  int N, int relu_flag) {
    __shared__ char lds[131072];
    constexpr int NT = 16;   // K = 1024 = NT * 64

    const int t = threadIdx.x;
    const int w = t >> 6, lane = t & 63;
    const int l = lane & 15, g = lane >> 4;
    const int m0 = blockIdx.x * 256, n0 = blockIdx.y * 256;
    const int wm = (w >> 2) * 128, wn = (w & 3) * 64;
    const int qx = (g ^ ((l >> 1) & 3)) * 16;
    const int qh8 = (((lane & 3) ^ ((lane >> 3) & 3)) * 8);
    const int srow = w * 32 + (lane >> 2);
    const short* Asrc = (const short*)A;
    const short* Bsrc = (const short*)Bt;

    f32x4 accL[4][4] = {};
    f32x4 accH[4][4] = {};
    short8 af[4], bf[4];

    auto stage = [&](int th, int j) {
        const int ks = j >> 1, mat = j & 1;
        char* slot = lds + ((th & 1) << 16) + (mat << 15) + (ks << 14);
        const short* mp = mat ? Bsrc : Asrc;
        const int rowb = (mat ? n0 : m0);
        const int kc = th * 64 + ks * 32 + qh8;
        gload_lds16(mp + (size_t)(rowb + srow) * 1024 + kc,      slot + (w * 2) * 1024);
        gload_lds16(mp + (size_t)(rowb + srow + 16) * 1024 + kc, slot + (w * 2 + 1) * 1024);
    };
    auto lda = [&](const char* rb, int mi, int ks) -> short8 {
        return *(const short8*)(rb + (ks << 14) + (wm + mi * 16 + l) * 64 + qx);
    };
    auto ldb = [&](const char* rb, int ni, int ks) -> short8 {
        return *(const short8*)(rb + 32768 + (ks << 14) + (wn + ni * 16 + l) * 64 + qx);
    };

    stage(0, 0); stage(0, 1); stage(0, 2); stage(0, 3); stage(1, 0); stage(1, 1);

    for (int it = 0; it < NT - 1; ++it) {
        const char* rb = lds + ((it & 1) << 16);
        PH_VM8; PH_BAR;
#pragma unroll
        for (int i = 0; i < 4; i++) af[i] = lda(rb, i, 0);
#pragma unroll
        for (int i = 0; i < 4; i++) bf[i] = ldb(rb, i, 0);
        stage(it + 1, 2);
        PH_LGKM;
        MM_BLOCK(accL);
#pragma unroll
        for (int i = 0; i < 4; i++) af[i] = lda(rb, 4 + i, 0);
        stage(it + 1, 3);
        PH_BAR; PH_LGKM;
        MM_BLOCK(accH);
        PH_VM8; PH_BAR;
#pragma unroll
        for (int i = 0; i < 4; i++) af[i] = lda(rb, i, 1);
#pragma unroll
        for (int i = 0; i < 4; i++) bf[i] = ldb(rb, i, 1);
        if (it + 2 < NT) stage(it + 2, 0);
        PH_LGKM;
        MM_BLOCK(accL);
#pragma unroll
        for (int i = 0; i < 4; i++) af[i] = lda(rb, 4 + i, 1);
        if (it + 2 < NT) stage(it + 2, 1);
        PH_BAR; PH_LGKM;
        MM_BLOCK(accH);
    }
    {
        const char* rb = lds + (((NT - 1) & 1) << 16);
        PH_VM4; PH_BAR;
#pragma unroll
        for (int i = 0; i < 4; i++) af[i] = lda(rb, i, 0);
#pragma unroll
        for (int i = 0; i < 4; i++) bf[i] = ldb(rb, i, 0);
        PH_LGKM;
        MM_BLOCK(accL);
#pragma unroll
        for (int i = 0; i < 4; i++) af[i] = lda(rb, 4 + i, 0);
        PH_BAR; PH_LGKM;
        MM_BLOCK(accH);
        PH_VM0; PH_BAR;
#pragma unroll
        for (int i = 0; i < 4; i++) af[i] = lda(rb, i, 1);
#pragma unroll
        for (int i = 0; i < 4; i++) bf[i] = ldb(rb, i, 1);
        PH_LGKM;
        MM_BLOCK(accL);
#pragma unroll
        for (int i = 0; i < 4; i++) af[i] = lda(rb, 4 + i, 1);
        PH_BAR; PH_LGKM;
        MM_BLOCK(accH);
    }

#pragma unroll
    for (int half = 0; half < 2; half++)
#pragma unroll
        for (int mi = 0; mi < 4; mi++)
#pragma unroll
            for (int r = 0; r < 4; r++) {
                const int grow = m0 + wm + (half * 4 + mi) * 16 + g * 4 + r;
                short* crow = (short*)(void*)Cp + (size_t)grow * N;
#pragma unroll
                for (int ni = 0; ni < 4; ni++) {
                    const int gcol = n0 + wn + ni * 16 + l;
                    float val = half ? accH[mi][ni][r] : accL[mi][ni][r];
                    if (bias) val += bias[gcol];
                    if (relu_flag) val = fmaxf(val, 0.f);
                    crow[gcol] = f2s(val);
                }
            }
}

// ---------------- MFMA flash attention: swapped QK^T + exp-fold (r12 proven) ----------
__global__ __launch_bounds__(256) void attn_kernel(const bf16* __restrict__ qkv,
                                                   bf16* __restrict__ o) {
    __shared__ short KsF[2][4096];
    __shared__ short Vt[64][72];
    __shared__ short Pl[4][32][76];

    const int bh = blockIdx.x;
    const int b = bh >> 4, h = bh & 15;
    const int qt = 15 - blockIdx.y;
    const int q0 = qt * 128;
    const size_t rbase = (size_t)b * 2048;
    const int hcol = h * 64;

    const int t = threadIdx.x;
    const int w = t >> 6;
    const int lane = t & 63;
    const int l = lane & 15;
    const int g = lane >> 4;
    const int sp = t >> 3;
    const int sb = (t & 7) * 8;

    const int qw0 = q0 + 32 * w;
    short8 qf[2][2];
#pragma unroll
    for (int mi = 0; mi < 2; mi++)
#pragma unroll
        for (int ks = 0; ks < 2; ks++) {
            const short* qp = (const short*)qkv +
                (rbase + qw0 + mi * 16 + l) * 3072 + hcol + ks * 32 + g * 8;
            short8 tv = *(const short8*)(const void*)qp;
            short8 sv;
#pragma unroll
            for (int e = 0; e < 8; e++) sv[e] = f2s(s2f(tv[e]) * 0.18033688f); // 0.125*log2(e)
            qf[mi][ks] = sv;
        }

    const int key_a = w * 16 + (lane >> 3);
    const int kd = (lane & 7) ^ ((lane >> 3) & 7);
    const short* kgA = (const short*)qkv + (rbase + key_a) * 3072 + 1024 + hcol + kd * 8;
    const short* kgB = kgA + 8 * 3072;

    f32x4 o_acc[2][4] = {};
    float l_sum[2] = {0.f, 0.f};
    const f32x4 z4 = {0.f, 0.f, 0.f, 0.f};

    const int kt_max = (q0 + 127) >> 6;

    gload_lds16(kgA, &KsF[0][w * 1024]);
    gload_lds16(kgB, &KsF[0][w * 1024 + 512]);

    for (int kt = 0; kt <= kt_max; kt++) {
        const int k0 = kt * 64;
        const short* vg = (const short*)qkv + (rbase + k0 + 2 * sp) * 3072 + 2048 + hcol + sb;
        short8 vv0 = *(const short8*)(const void*)vg;
        short8 vv1 = *(const short8*)(const void*)(vg + 3072);
        PH_BAR;
        {
            const int kp = (kt < kt_max) ? (kt + 1) : kt;
            const size_t kof = (size_t)kp * 64 * 3072;
            gload_lds16(kgA + kof, &KsF[(kt + 1) & 1][w * 1024]);
            gload_lds16(kgB + kof, &KsF[(kt + 1) & 1][w * 1024 + 512]);
        }
        asm volatile("s_waitcnt vmcnt(2)" ::: "memory");
        __builtin_amdgcn_sched_barrier(0);
        {
            const int key = 2 * sp;
            const int cbk = key >> 3;
            const int kin = key & 7;
#pragma unroll
            for (int j = 0; j < 8; j++) {
                const int d = sb + j;
                const int col = ((cbk ^ (d >> 3)) << 3) + kin;
                int pk = (int)(unsigned short)vv0[j] | ((int)(unsigned short)vv1[j] << 16);
                *(int*)(void*)&Vt[d][col] = pk;
            }
        }
        asm volatile("s_waitcnt lgkmcnt(0)" ::: "memory");
        __builtin_amdgcn_sched_barrier(0);
        PH_BAR;

        if (k0 <= qw0 + 31) {
            const short* kb = &KsF[kt & 1][0];
            const bool needMask = (k0 + 63 > qw0);
            f32x4 s_acc[2][4];
            {
                short8 kf[4];
#pragma unroll
                for (int ni = 0; ni < 4; ni++) {
                    const int key = ni * 16 + l;
                    const int c = key * 8 + (g ^ (key & 7));
                    kf[ni] = *(const short8*)&kb[c * 8];
                }
#pragma unroll
                for (int mi = 0; mi < 2; mi++)
#pragma unroll
                    for (int ni = 0; ni < 4; ni++)
                        s_acc[mi][ni] = __builtin_amdgcn_mfma_f32_16x16x32_bf16(
                            kf[ni], qf[mi][0], z4, 0, 0, 0);
            }
            {
                short8 kf[4];
#pragma unroll
                for (int ni = 0; ni < 4; ni++) {
                    const int key = ni * 16 + l;
                    const int c = key * 8 + ((4 + g) ^ (key & 7));
                    kf[ni] = *(const short8*)&kb[c * 8];
                }
#pragma unroll
                for (int mi = 0; mi < 2; mi++)
#pragma unroll
                    for (int ni = 0; ni < 4; ni++)
                        s_acc[mi][ni] = __builtin_amdgcn_mfma_f32_16x16x32_bf16(
                            kf[ni], qf[mi][1], s_acc[mi][ni], 0, 0, 0);
            }
#pragma unroll
            for (int mi = 0; mi < 2; mi++) {
                const int qg = qw0 + mi * 16 + l;
#pragma unroll
                for (int ni = 0; ni < 4; ni++) {
                    const int keyb = k0 + ni * 16 + 4 * g;
                    s16x4 pv;
#pragma unroll
                    for (int r = 0; r < 4; r++) {
                        float s = s_acc[mi][ni][r];
                        if (needMask && (keyb + r > qg)) s = -1e30f;
                        float pe;
                        asm("v_exp_f32 %0, %1" : "=v"(pe) : "v"(s));  // pe = 2^s
                        l_sum[mi] += pe;
                        pv[r] = f2s(pe);
                    }
                    *(s16x4*)(void*)&Pl[w][mi * 16 + l][ni * 16 + 4 * g] = pv;
                }
            }
#pragma unroll
            for (int ks = 0; ks < 2; ks++) {
                short8 pf[2], vf[4];
#pragma unroll
                for (int mi = 0; mi < 2; mi++)
                    pf[mi] = *(const short8*)&Pl[w][mi * 16 + l][ks * 32 + g * 8];
#pragma unroll
                for (int nd = 0; nd < 4; nd++) {
                    const int d = nd * 16 + l;
                    const int cb = ks * 4 + g;
                    vf[nd] = *(const short8*)&Vt[d][((cb ^ (d >> 3)) << 3)];
                }
#pragma unroll
                for (int mi = 0; mi < 2; mi++)
#pragma unroll
                    for (int nd = 0; nd < 4; nd++)
                        o_acc[mi][nd] = __builtin_amdgcn_mfma_f32_16x16x32_bf16(
                            pf[mi], vf[nd], o_acc[mi][nd], 0, 0, 0);
            }
        }
    }

#pragma unroll
    for (int mi = 0; mi < 2; mi++) {
        l_sum[mi] += __shfl_xor(l_sum[mi], 16);
        l_sum[mi] += __shfl_xor(l_sum[mi], 32);
    }

#pragma unroll
    for (int mi = 0; mi < 2; mi++)
#pragma unroll
        for (int r = 0; r < 4; r++) {
            const float lsum = __shfl(l_sum[mi], 4 * g + r);
            const float inv = 1.0f / lsum;
            const int qg = qw0 + mi * 16 + 4 * g + r;
            short* op = (short*)(void*)(o + (rbase + qg) * 1024 + hcol);
#pragma unroll
            for (int nd = 0; nd < 4; nd++)
                op[nd * 16 + l] = f2s(o_acc[mi][nd][r] * inv);
        }
}

// ---------------- launch ----------------
extern "C" void kernel_launch(void* const* d_in, const int* in_sizes, int n_in,
                              void* d_out, int out_size, void* d_ws, size_t ws_size,
                              hipStream_t stream) {
    const float* x   = (const float*)d_in[0];
    const float* Wq  = (const float*)d_in[1];
    const float* Wk  = (const float*)d_in[2];
    const float* Wv  = (const float*)d_in[3];
    const float* Wo  = (const float*)d_in[4];
    const float* bo  = (const float*)d_in[5];
    const float* W1  = (const float*)d_in[6];
    const float* b1  = (const float*)d_in[7];
    const float* W2  = (const float*)d_in[8];
    const float* b2  = (const float*)d_in[9];
    const float* g1  = (const float*)d_in[10];
    const float* be1 = (const float*)d_in[11];
    const float* g2  = (const float*)d_in[12];
    const float* be2 = (const float*)d_in[13];

    char* ws = (char*)d_ws;
    const size_t MB = (size_t)1024 * 1024;
    bf16*  s0  = (bf16*)(ws);               // h -> attn-out (16 MB)
    bf16*  qkv = (bf16*)(ws + 16 * MB);     // [8192][3072] bf16 (48 MB)
    short* WoT = (short*)(ws + 16 * MB);    // after attn (2 MB)
    short* W1T = (short*)(ws);              // after Wo GEMM: [4096][1024] (8 MB)
    short* W2T = (short*)(ws + 8 * MB);     // [1024][4096] (8 MB)
    bf16*  h2  = (bf16*)(ws + 16 * MB);     // after Wo GEMM (16 MB)
    bf16*  m1  = (bf16*)(ws + 32 * MB);     // MLP half intermediate (32 MB)
    short* WT  = (short*)d_out;             // QKV weightT scratch (6 MB, dies pre-x1)
    float* x1  = (float*)d_out;

    const int M = 8192, C = 1024, F = 4096, MH = 4096;

    tconv_kernel<<<dim3(16, 16), 256, 0, stream>>>(Wq, WT,                   C, C);
    tconv_kernel<<<dim3(16, 16), 256, 0, stream>>>(Wk, WT + 1024 * 1024,     C, C);
    tconv_kernel<<<dim3(16, 16), 256, 0, stream>>>(Wv, WT + 2 * 1024 * 1024, C, C);

    ln_kernel<<<M / 4, 256, 0, stream>>>(x, g1, be1, s0);

    // fused QKV: [8192][1024] @ [1024][3072] -> qkv bf16 (8-phase 256^2 core)
    gemm256<<<dim3(M / 256, 3072 / 256), 512, 0, stream>>>(
        s0, (const bf16*)WT, nullptr, qkv, 3072, 0);

    attn_kernel<<<dim3(64, 16), 256, 0, stream>>>(qkv, s0);

    // WoT into qkv region (dead); x1 = x + attn @ Wo + bo -> d_out fp32
    // Wo: 8192x1024 @ K=1024 -> gemm128 4-phase (512 blocks, 2/CU)
    tconv_kernel<<<dim3(16, 16), 256, 0, stream>>>(Wo, WoT, C, C);
    gemm128<<<dim3(M / 128, C / 128), 256, 0, stream>>>(
        s0, (const bf16*)WoT, bo, x, x1, 1, 0, C, C, 0);

    tconv_kernel<<<dim3(64, 16), 256, 0, stream>>>(W1, W1T, C, F);
    tconv_kernel<<<dim3(16, 64), 256, 0, stream>>>(W2, W2T, F, C);

    ln_kernel<<<M / 4, 256, 0, stream>>>(x1, g2, be2, h2);

    for (int half = 0; half < 2; half++) {
        const bf16* Ah = h2 + (size_t)half * MH * C;
        // W1: 4096x4096 @ K=1024 -> 256 blocks = 1/CU, 8-phase 256^2 core
        gemm256<<<dim3(MH / 256, F / 256), 512, 0, stream>>>(
            Ah, (const bf16*)W1T, b1, m1, F, 1);
        // W2: 4096x1024 @ K=4096 -> 128x64 tile (512 blocks = 2/CU, NT=64)
        gemm128n64<<<dim3(MH / 128, C / 64), 256, 0, stream>>>(
            m1, (const bf16*)W2T, b2, x1, d_out, 1, half * MH, C, F, 0);
    }
}